// Round 1
// baseline (413.199 us; speedup 1.0000x reference)
//
#include <hip/hip_runtime.h>
#include <hip/hip_bf16.h>

// MQA cross-attention, B=4, LQ=LK=2048, D=1024, H=16, HD=64.
// Pipeline: cast(x,text)->bf16 ; transpose-cast(Wq,Wkv)->bf16 [N][K] ;
//   bf16 MFMA GEMM -> Q (scaled 1/8), K (row-XOR-swizzled), V (PV-blocked layout) ;
//   flash attention (4 waves x 16 q-rows, KVBLK=32, online softmax).

typedef unsigned short u16;
typedef unsigned int u32;

typedef __attribute__((ext_vector_type(8))) __bf16 bf16x8;
typedef __attribute__((ext_vector_type(4))) float f32x4;
typedef __attribute__((ext_vector_type(4))) float f4;
typedef __attribute__((ext_vector_type(4))) unsigned short u16x4;

#define DEVI __device__ __forceinline__

DEVI u16 f2b(float f) {  // fp32 -> bf16 RNE (finite inputs)
  u32 u = __float_as_uint(f);
  return (u16)((u + 0x7fffu + ((u >> 16) & 1u)) >> 16);
}

DEVI void gld_lds16(void* lds, const void* g) {
  // async global->LDS, 16B/lane; dest is wave-uniform base + lane*16
  __builtin_amdgcn_global_load_lds(
      (const __attribute__((address_space(1))) u32*)g,
      (__attribute__((address_space(3))) u32*)lds, 16, 0, 0);
}

// ---------------- cast f32 -> bf16 ----------------
__global__ void k_cast(const float* __restrict__ in, u16* __restrict__ out, int n4) {
  int i = blockIdx.x * blockDim.x + threadIdx.x;
  int stride = gridDim.x * blockDim.x;
  for (; i < n4; i += stride) {
    f4 v = ((const f4*)in)[i];
    u16x4 o;
    o.x = f2b(v.x); o.y = f2b(v.y); o.z = f2b(v.z); o.w = f2b(v.w);
    ((u16x4*)out)[i] = o;
  }
}

// -------- transpose + cast: in [K][N] f32 -> out [N][K] bf16 --------
__global__ void k_transpose_cast(const float* __restrict__ in, u16* __restrict__ out,
                                 int K, int N) {
  __shared__ float tile[32][33];
  int n0 = blockIdx.x * 32, k0 = blockIdx.y * 32;
  int tx = threadIdx.x, ty = threadIdx.y;  // block (32,8)
#pragma unroll
  for (int j = 0; j < 32; j += 8)
    tile[ty + j][tx] = in[(size_t)(k0 + ty + j) * N + n0 + tx];
  __syncthreads();
#pragma unroll
  for (int j = 0; j < 32; j += 8)
    out[(size_t)(n0 + ty + j) * K + k0 + tx] = f2b(tile[tx][ty + j]);
}

// ---------------- bf16 GEMM: C[M,N] = A[M,1024] @ Bt[N,1024]^T + bias ----------------
// EPI 0: Q epilogue   -> out0 = QG [b][h][2048][64] bf16, value*(1/8)
// EPI 1: KV epilogue  -> n<1024: K -> out0 = KG [b][h][2048] rows of 128B, XOR-swizzled
//                        n>=1024: V -> out1 = VG [b][h][64 blk][4096B] PV-blocked
template <int EPI>
__global__ __launch_bounds__(256) void k_gemm(
    const u16* __restrict__ A, const u16* __restrict__ Bt,
    const float* __restrict__ bias, u16* __restrict__ out0, u16* __restrict__ out1) {
  __shared__ alignas(16) char As[2][8192];
  __shared__ alignas(16) char Bs[2][8192];
  const int tid = threadIdx.x;
  const int w = tid >> 6, l = tid & 63;
  const int wr = w >> 1, wc = w & 1;
  const int m0 = blockIdx.y << 7, n0 = blockIdx.x << 7;

  // staging: LDS linear [128 rows][64B], source pre-XOR-swizzled (^((row&3)<<4))
  u32 soff[2], doff[2];
#pragma unroll
  for (int i = 0; i < 2; i++) {
    u32 o = (u32)(i * 4096 + tid * 16);
    u32 row = o >> 6;
    soff[i] = row * 2048 + ((o & 63) ^ ((row & 3) << 4));
    doff[i] = o;
  }
  const char* Aorig = (const char*)A + (size_t)m0 * 2048;
  const char* Borig = (const char*)Bt + (size_t)n0 * 2048;

  f32x4 acc[4][4];
#pragma unroll
  for (int i = 0; i < 4; i++)
#pragma unroll
    for (int j = 0; j < 4; j++) acc[i][j] = (f32x4){0.f, 0.f, 0.f, 0.f};

  const u32 co = (u32)(((l >> 4) ^ (l & 3)) << 4);  // swizzled k-chunk
  const u32 arow = (u32)(wr * 64 + (l & 15)) * 64;
  const u32 brow = (u32)(wc * 64 + (l & 15)) * 64;

#pragma unroll
  for (int i = 0; i < 2; i++) {
    gld_lds16(&As[0][doff[i]], Aorig + soff[i]);
    gld_lds16(&Bs[0][doff[i]], Borig + soff[i]);
  }
  __syncthreads();
  int buf = 0;
  for (int kt = 0; kt < 32; kt++) {
    if (kt < 31) {
#pragma unroll
      for (int i = 0; i < 2; i++) {
        gld_lds16(&As[buf ^ 1][doff[i]], Aorig + (u32)(kt + 1) * 64 + soff[i]);
        gld_lds16(&Bs[buf ^ 1][doff[i]], Borig + (u32)(kt + 1) * 64 + soff[i]);
      }
    }
    bf16x8 af[4], bfr[4];
#pragma unroll
    for (int t = 0; t < 4; t++) {
      af[t] = *(const bf16x8*)&As[buf][arow + (u32)t * 1024 + co];
      bfr[t] = *(const bf16x8*)&Bs[buf][brow + (u32)t * 1024 + co];
    }
#pragma unroll
    for (int i = 0; i < 4; i++)
#pragma unroll
      for (int j = 0; j < 4; j++)
        acc[i][j] = __builtin_amdgcn_mfma_f32_16x16x32_bf16(af[i], bfr[j], acc[i][j], 0, 0, 0);
    __syncthreads();
    buf ^= 1;
  }

  // epilogue: C row = m0+wr*64+i*16+4*(l>>4)+r ; col = n0+wc*64+j*16+(l&15)
#pragma unroll
  for (int i = 0; i < 4; i++) {
    const int mbase = m0 + wr * 64 + i * 16 + ((l >> 4) << 2);
    const int bb = mbase >> 11;      // batch
    const int mrow = mbase & 2047;   // q or lk
#pragma unroll
    for (int j = 0; j < 4; j++) {
      const int n = n0 + wc * 64 + j * 16 + (l & 15);
      const float bv = bias[n];
      if (EPI == 0) {
        const int h = n >> 6, hd = n & 63;
        u16* dst = out0 + ((((size_t)bb * 16 + h) * 2048 + mrow) << 6) + hd;
#pragma unroll
        for (int r = 0; r < 4; r++) dst[(size_t)r << 6] = f2b((acc[i][j][r] + bv) * 0.125f);
      } else if (n < 1024) {  // K: rows of 128B, in-row byte ^= ((lk&7)<<4)
        const int h = n >> 6, d = n & 63;
        char* base = (char*)out0 + ((((size_t)bb * 16 + h) * 2048 + mrow) << 7);
#pragma unroll
        for (int r = 0; r < 4; r++) {
          u32 off = (u32)r * 128 + (((u32)d * 2) ^ (((u32)(mrow + r) & 7) << 4));
          *(u16*)(base + off) = f2b(acc[i][j][r] + bv);
        }
      } else {  // V: block(lk>>5) of 4KB: (hd>>4)*1024+((lk>>3)&3)*256+(hd&15)*16+(lk&7)*2
        const int nn = n - 1024;
        const int h = nn >> 6, hd = nn & 63;
        u16x4 pk;
        pk.x = f2b(acc[i][j][0] + bv);
        pk.y = f2b(acc[i][j][1] + bv);
        pk.z = f2b(acc[i][j][2] + bv);
        pk.w = f2b(acc[i][j][3] + bv);
        char* base = (char*)out1 + (((size_t)bb * 16 + h) * 64 + (mrow >> 5)) * 4096;
        u32 off = ((u32)(hd >> 4) << 10) + (((u32)(mrow >> 3) & 3) << 8) +
                  ((u32)(hd & 15) << 4) + (((u32)mrow & 7) << 1);
        *(u16x4*)(base + off) = pk;
      }
    }
  }
}

// ---------------- flash attention ----------------
// grid = B*H*(LQ/64); block 256 = 4 waves, wave w owns q rows w*16..w*16+15
__global__ __launch_bounds__(256) void k_attn(
    const u16* __restrict__ QG, const u16* __restrict__ KG, const u16* __restrict__ VG,
    float* __restrict__ out) {
  __shared__ alignas(16) char Ks[2][4096];
  __shared__ alignas(16) char Vs[2][4096];
  __shared__ alignas(16) char Ps[4][1280];  // per-wave P[16 q][32 k] bf16, row stride 80B
  const int tid = threadIdx.x, w = tid >> 6, l = tid & 63;
  const int qt = blockIdx.x & 31;
  const int hh = (blockIdx.x >> 5) & 15;
  const int b = blockIdx.x >> 9;
  const size_t bh = (size_t)b * 16 + hh;

  // Q A-frags in regs: row=(l&15), d=8*(l>>4)+e (+32 for half 1); Q pre-scaled by 1/8
  const u16* Qp = QG + ((bh * 2048 + (size_t)(qt * 64 + w * 16 + (l & 15))) << 6) + ((l >> 4) << 3);
  const bf16x8 qf0 = *(const bf16x8*)Qp;
  const bf16x8 qf1 = *(const bf16x8*)(Qp + 32);

  const char* Kbase = (const char*)KG + (bh << 18);  // 2048 rows * 128B
  const char* Vbase = (const char*)VG + (bh << 18);  // 64 blocks * 4096B

  float m_[4], ls[4];
  f32x4 o_[4];
#pragma unroll
  for (int r = 0; r < 4; r++) { m_[r] = -__builtin_inff(); ls[r] = 0.f; }
#pragma unroll
  for (int c = 0; c < 4; c++) o_[c] = (f32x4){0.f, 0.f, 0.f, 0.f};

  gld_lds16(&Ks[0][tid * 16], Kbase + tid * 16);
  gld_lds16(&Vs[0][tid * 16], Vbase + tid * 16);
  __syncthreads();

  int buf = 0;
  const u32 ksw = ((u32)(l & 7)) << 4;        // K row swizzle (k&7 == l&7)
  const u32 kro0 = ((u32)(l & 15)) << 7;      // k row * 128
  const u32 kin0 = ((u32)(l >> 4)) << 4;      // d-chunk byte

  for (int kb = 0; kb < 64; kb++) {
    if (kb < 63) {
      gld_lds16(&Ks[buf ^ 1][tid * 16], Kbase + (size_t)(kb + 1) * 4096 + tid * 16);
      gld_lds16(&Vs[buf ^ 1][tid * 16], Vbase + (size_t)(kb + 1) * 4096 + tid * 16);
    }
    // S^ = Q . K^T : s[t][r] = S[q=4*(l>>4)+r][k=16t+(l&15)]
    f32x4 s[2];
#pragma unroll
    for (int t = 0; t < 2; t++) {
      const char* kr = &Ks[buf][kro0 + (u32)t * 2048];
      bf16x8 kf0 = *(const bf16x8*)(kr + (kin0 ^ ksw));
      bf16x8 kf1 = *(const bf16x8*)(kr + ((kin0 + 64) ^ ksw));
      f32x4 z = (f32x4){0.f, 0.f, 0.f, 0.f};
      s[t] = __builtin_amdgcn_mfma_f32_16x16x32_bf16(qf0, kf0, z, 0, 0, 0);
      s[t] = __builtin_amdgcn_mfma_f32_16x16x32_bf16(qf1, kf1, s[t], 0, 0, 0);
    }
    // online softmax over k (16-lane butterfly within row group)
    float corr[4], p0[4], p1[4];
#pragma unroll
    for (int r = 0; r < 4; r++) {
      float t0 = fmaxf(s[0][r], s[1][r]);
      t0 = fmaxf(t0, __shfl_xor(t0, 1));
      t0 = fmaxf(t0, __shfl_xor(t0, 2));
      t0 = fmaxf(t0, __shfl_xor(t0, 4));
      t0 = fmaxf(t0, __shfl_xor(t0, 8));
      float mn = fmaxf(m_[r], t0);
      corr[r] = __expf(m_[r] - mn);
      p0[r] = __expf(s[0][r] - mn);
      p1[r] = __expf(s[1][r] - mn);
      float rsum = p0[r] + p1[r];
      rsum += __shfl_xor(rsum, 1);
      rsum += __shfl_xor(rsum, 2);
      rsum += __shfl_xor(rsum, 4);
      rsum += __shfl_xor(rsum, 8);
      ls[r] = ls[r] * corr[r] + rsum;
      m_[r] = mn;
    }
#pragma unroll
    for (int c = 0; c < 4; c++)
#pragma unroll
      for (int r = 0; r < 4; r++) o_[c][r] *= corr[r];

    // P -> LDS (wave-private), re-fragment as MFMA A operand
    char* Pw = Ps[w];
    const u32 pq = ((u32)(l >> 4)) << 2;
#pragma unroll
    for (int r = 0; r < 4; r++) {
      *(u16*)(Pw + (pq + r) * 80 + ((l & 15) << 1)) = f2b(p0[r]);
      *(u16*)(Pw + (pq + r) * 80 + 32 + ((l & 15) << 1)) = f2b(p1[r]);
    }
    asm volatile("s_waitcnt lgkmcnt(0)" ::: "memory");  // wave-private: no barrier needed
    bf16x8 pf = *(const bf16x8*)(Ps[w] + (u32)(l & 15) * 80 + ((l >> 4) << 4));
#pragma unroll
    for (int c = 0; c < 4; c++) {
      bf16x8 vf = *(const bf16x8*)&Vs[buf][c * 1024 + l * 16];  // coalesced, conflict-free
      o_[c] = __builtin_amdgcn_mfma_f32_16x16x32_bf16(pf, vf, o_[c], 0, 0, 0);
    }
    __syncthreads();
    buf ^= 1;
  }

  const int qrow = qt * 64 + w * 16 + ((l >> 4) << 2);
  float* obase = out + ((size_t)b * 2048 + qrow) * 1024 + hh * 64 + (l & 15);
#pragma unroll
  for (int r = 0; r < 4; r++) {
    float inv = 1.0f / ls[r];
#pragma unroll
    for (int c = 0; c < 4; c++) obase[(size_t)r * 1024 + c * 16] = o_[c][r] * inv;
  }
}

extern "C" void kernel_launch(void* const* d_in, const int* in_sizes, int n_in,
                              void* d_out, int out_size, void* d_ws, size_t ws_size,
                              hipStream_t stream) {
  const float* x = (const float*)d_in[0];
  const float* text = (const float*)d_in[1];
  const float* Wq = (const float*)d_in[2];
  const float* bq = (const float*)d_in[3];
  const float* Wkv = (const float*)d_in[4];
  const float* bkv = (const float*)d_in[5];
  float* out = (float*)d_out;
  char* ws = (char*)d_ws;

  const size_t MiB = 1u << 20;
  u16* XB = (u16*)(ws + 0 * MiB);     // x bf16       [8192][1024]   16 MiB
  u16* TB = (u16*)(ws + 16 * MiB);    // text bf16    [8192][1024]   16 MiB
  u16* WQT = (u16*)(ws + 32 * MiB);   // Wq^T bf16    [1024][1024]    2 MiB
  u16* WKVT = (u16*)(ws + 34 * MiB);  // Wkv^T bf16   [2048][1024]    4 MiB
  u16* QG = (u16*)(ws + 38 * MiB);    // Q  bf16      [4][16][2048][64]
  u16* KG = (u16*)(ws + 54 * MiB);    // K  bf16      swizzled rows
  u16* VG = (u16*)(ws + 70 * MiB);    // V  bf16      PV-blocked     (end: 86 MiB)

  k_cast<<<2048, 256, 0, stream>>>(x, XB, 2097152);
  k_cast<<<2048, 256, 0, stream>>>(text, TB, 2097152);
  k_transpose_cast<<<dim3(32, 32), dim3(32, 8), 0, stream>>>(Wq, WQT, 1024, 1024);
  k_transpose_cast<<<dim3(64, 32), dim3(32, 8), 0, stream>>>(Wkv, WKVT, 1024, 2048);
  k_gemm<0><<<dim3(8, 64), 256, 0, stream>>>(XB, WQT, bq, QG, (u16*)nullptr);
  k_gemm<1><<<dim3(16, 64), 256, 0, stream>>>(TB, WKVT, bkv, KG, VG);
  k_attn<<<2048, 256, 0, stream>>>(QG, KG, VG, out);
}

// Round 2
// 276.223 us; speedup vs baseline: 1.4959x; 1.4959x over previous
//
#include <hip/hip_runtime.h>
#include <hip/hip_bf16.h>

// MQA cross-attention, B=4, LQ=LK=2048, D=1024, H=16, HD=64.
// Pipeline: cast(x,text)->bf16 ; transpose-cast(Wq,Wkv)->bf16 [N][K] ;
//   bf16 MFMA GEMM -> Q (scaled 1/8), K (row-XOR-swizzled bf16), V (f16, PV-fragment layout) ;
//   flash attention: swapped QK^T (S^T in regs), in-register softmax (2 shfl),
//   PV via 16x16x16 f16 MFMA with P kept in registers.

typedef unsigned short u16;
typedef unsigned int u32;

typedef __attribute__((ext_vector_type(8))) __bf16 bf16x8;
typedef __attribute__((ext_vector_type(4))) _Float16 f16x4;
typedef __attribute__((ext_vector_type(4))) float f32x4;
typedef __attribute__((ext_vector_type(4))) float f4;
typedef __attribute__((ext_vector_type(4))) unsigned short u16x4;

#define DEVI __device__ __forceinline__

DEVI u16 f2b(float f) {  // fp32 -> bf16 RNE (finite inputs)
  u32 u = __float_as_uint(f);
  return (u16)((u + 0x7fffu + ((u >> 16) & 1u)) >> 16);
}

DEVI u16 f2h(float f) {  // fp32 -> f16 bits
  _Float16 h = (_Float16)f;
  return __builtin_bit_cast(u16, h);
}

DEVI void gld_lds16(void* lds, const void* g) {
  // async global->LDS, 16B/lane; dest is wave-uniform base + lane*16
  __builtin_amdgcn_global_load_lds(
      (const __attribute__((address_space(1))) u32*)g,
      (__attribute__((address_space(3))) u32*)lds, 16, 0, 0);
}

// ---------------- cast f32 -> bf16 ----------------
__global__ void k_cast(const float* __restrict__ in, u16* __restrict__ out, int n4) {
  int i = blockIdx.x * blockDim.x + threadIdx.x;
  int stride = gridDim.x * blockDim.x;
  for (; i < n4; i += stride) {
    f4 v = ((const f4*)in)[i];
    u16x4 o;
    o.x = f2b(v.x); o.y = f2b(v.y); o.z = f2b(v.z); o.w = f2b(v.w);
    ((u16x4*)out)[i] = o;
  }
}

// -------- transpose + cast: in [K][N] f32 -> out [N][K] bf16 --------
__global__ void k_transpose_cast(const float* __restrict__ in, u16* __restrict__ out,
                                 int K, int N) {
  __shared__ float tile[32][33];
  int n0 = blockIdx.x * 32, k0 = blockIdx.y * 32;
  int tx = threadIdx.x, ty = threadIdx.y;  // block (32,8)
#pragma unroll
  for (int j = 0; j < 32; j += 8)
    tile[ty + j][tx] = in[(size_t)(k0 + ty + j) * N + n0 + tx];
  __syncthreads();
#pragma unroll
  for (int j = 0; j < 32; j += 8)
    out[(size_t)(n0 + ty + j) * K + k0 + tx] = f2b(tile[tx][ty + j]);
}

// ---------------- bf16 GEMM: C[M,N] = A[M,1024] @ Bt[N,1024]^T + bias ----------------
// EPI 0: Q epilogue   -> out0 = QG [b][h][2048][64] bf16, value*(1/8)
// EPI 1: KV epilogue  -> n<1024: K -> out0 = KG [b][h][2048] rows of 128B, XOR-swizzled
//                        n>=1024: V -> out1 = VG f16, PV-fragment blocked layout
template <int EPI>
__global__ __launch_bounds__(256) void k_gemm(
    const u16* __restrict__ A, const u16* __restrict__ Bt,
    const float* __restrict__ bias, u16* __restrict__ out0, u16* __restrict__ out1) {
  __shared__ alignas(16) char As[2][8192];
  __shared__ alignas(16) char Bs[2][8192];
  const int tid = threadIdx.x;
  const int w = tid >> 6, l = tid & 63;
  const int wr = w >> 1, wc = w & 1;
  const int m0 = blockIdx.y << 7, n0 = blockIdx.x << 7;

  // staging: LDS linear [128 rows][64B], source pre-XOR-swizzled (^((row&3)<<4))
  u32 soff[2], doff[2];
#pragma unroll
  for (int i = 0; i < 2; i++) {
    u32 o = (u32)(i * 4096 + tid * 16);
    u32 row = o >> 6;
    soff[i] = row * 2048 + ((o & 63) ^ ((row & 3) << 4));
    doff[i] = o;
  }
  const char* Aorig = (const char*)A + (size_t)m0 * 2048;
  const char* Borig = (const char*)Bt + (size_t)n0 * 2048;

  f32x4 acc[4][4];
#pragma unroll
  for (int i = 0; i < 4; i++)
#pragma unroll
    for (int j = 0; j < 4; j++) acc[i][j] = (f32x4){0.f, 0.f, 0.f, 0.f};

  const u32 co = (u32)(((l >> 4) ^ (l & 3)) << 4);  // swizzled k-chunk
  const u32 arow = (u32)(wr * 64 + (l & 15)) * 64;
  const u32 brow = (u32)(wc * 64 + (l & 15)) * 64;

#pragma unroll
  for (int i = 0; i < 2; i++) {
    gld_lds16(&As[0][doff[i]], Aorig + soff[i]);
    gld_lds16(&Bs[0][doff[i]], Borig + soff[i]);
  }
  __syncthreads();
  int buf = 0;
  for (int kt = 0; kt < 32; kt++) {
    if (kt < 31) {
#pragma unroll
      for (int i = 0; i < 2; i++) {
        gld_lds16(&As[buf ^ 1][doff[i]], Aorig + (u32)(kt + 1) * 64 + soff[i]);
        gld_lds16(&Bs[buf ^ 1][doff[i]], Borig + (u32)(kt + 1) * 64 + soff[i]);
      }
    }
    bf16x8 af[4], bfr[4];
#pragma unroll
    for (int t = 0; t < 4; t++) {
      af[t] = *(const bf16x8*)&As[buf][arow + (u32)t * 1024 + co];
      bfr[t] = *(const bf16x8*)&Bs[buf][brow + (u32)t * 1024 + co];
    }
#pragma unroll
    for (int i = 0; i < 4; i++)
#pragma unroll
      for (int j = 0; j < 4; j++)
        acc[i][j] = __builtin_amdgcn_mfma_f32_16x16x32_bf16(af[i], bfr[j], acc[i][j], 0, 0, 0);
    __syncthreads();
    buf ^= 1;
  }

  // epilogue: C row = m0+wr*64+i*16+4*(l>>4)+r ; col = n0+wc*64+j*16+(l&15)
#pragma unroll
  for (int i = 0; i < 4; i++) {
    const int mbase = m0 + wr * 64 + i * 16 + ((l >> 4) << 2);
    const int bb = mbase >> 11;      // batch
    const int mrow = mbase & 2047;   // q or lk (mrow%4==0)
#pragma unroll
    for (int j = 0; j < 4; j++) {
      const int n = n0 + wc * 64 + j * 16 + (l & 15);
      const float bv = bias[n];
      if (EPI == 0) {
        const int h = n >> 6, hd = n & 63;
        u16* dst = out0 + ((((size_t)bb * 16 + h) * 2048 + mrow) << 6) + hd;
#pragma unroll
        for (int r = 0; r < 4; r++) dst[(size_t)r << 6] = f2b((acc[i][j][r] + bv) * 0.125f);
      } else if (n < 1024) {  // K: rows of 128B, in-row byte ^= ((lk&7)<<4)
        const int h = n >> 6, d = n & 63;
        char* base = (char*)out0 + ((((size_t)bb * 16 + h) * 2048 + mrow) << 7);
#pragma unroll
        for (int r = 0; r < 4; r++) {
          u32 off = (u32)r * 128 + (((u32)d * 2) ^ (((u32)(mrow + r) & 7) << 4));
          *(u16*)(base + off) = f2b(acc[i][j][r] + bv);
        }
      } else {
        // V (f16): PV-fragment layout. Element V[lk][hd] lives at byte
        //   blk(lk>>5)*4096 + ((lk>>4)&1)*2048 + (hd>>4)*512 + ((lk>>2)&3)*128 + (hd&15)*8 + (lk&3)*2
        // -> the 4 rows r=0..3 of one acc column are one contiguous 8B fragment.
        const int nn = n - 1024;
        const int h = nn >> 6, hd = nn & 63;
        u16x4 pk;
        pk.x = f2h(acc[i][j][0] + bv);
        pk.y = f2h(acc[i][j][1] + bv);
        pk.z = f2h(acc[i][j][2] + bv);
        pk.w = f2h(acc[i][j][3] + bv);
        char* base = (char*)out1 + (((size_t)bb * 16 + h) << 18);
        u32 off = ((u32)(mrow >> 5) << 12) + (((u32)(mrow >> 4) & 1) << 11) +
                  ((u32)(hd >> 4) << 9) + (((u32)(mrow >> 2) & 3) << 7) +
                  ((u32)(hd & 15) << 3);
        *(u16x4*)(base + off) = pk;
      }
    }
  }
}

// ---------------- flash attention ----------------
// grid = B*H*(LQ/64); block 256 = 4 waves, wave w owns q rows w*16..w*16+15.
// Swapped QK^T: S^T[k][q] in regs (q = lane&15); softmax in-register with 2 shfl;
// P^T stays in regs as the B-fragment of 16x16x16 f16 MFMA; O^T accumulated.
__global__ __launch_bounds__(256) void k_attn(
    const u16* __restrict__ QG, const u16* __restrict__ KG, const u16* __restrict__ VG,
    float* __restrict__ out) {
  __shared__ alignas(16) char Ks[2][4096];
  __shared__ alignas(16) char Vs[2][4096];
  const int tid = threadIdx.x, w = tid >> 6, l = tid & 63;
  const int g = l >> 4, q = l & 15;
  const int qt = blockIdx.x & 31;
  const int hh = (blockIdx.x >> 5) & 15;
  const int b = blockIdx.x >> 9;
  const size_t bh = (size_t)b * 16 + hh;

  // Q B-frags in regs: lane holds Q[q][d=8g+e] (+32 for half 1); Q pre-scaled by 1/8
  const u16* Qp = QG + ((bh * 2048 + (size_t)(qt * 64 + w * 16 + q)) << 6) + (g << 3);
  const bf16x8 qf0 = *(const bf16x8*)Qp;
  const bf16x8 qf1 = *(const bf16x8*)(Qp + 32);

  const char* Kbase = (const char*)KG + (bh << 18);  // 2048 rows * 128B
  const char* Vbase = (const char*)VG + (bh << 18);  // 64 blocks * 4096B (f16 frag layout)

  float m_ = -__builtin_inff(), ls = 0.f;
  f32x4 o_[4];  // o_[c][r] = O^T[d=16c+4g+r][q]
#pragma unroll
  for (int c = 0; c < 4; c++) o_[c] = (f32x4){0.f, 0.f, 0.f, 0.f};

  gld_lds16(&Ks[0][tid * 16], Kbase + tid * 16);
  gld_lds16(&Vs[0][tid * 16], Vbase + tid * 16);
  __syncthreads();

  int buf = 0;
  const u32 ksw = ((u32)(l & 7)) << 4;  // K row swizzle key (row&7 == l&7)
  const u32 kro = ((u32)q) << 7;        // K row * 128B
  const u32 kin = ((u32)g) << 4;        // d-chunk byte

  for (int kb = 0; kb < 64; kb++) {
    if (kb < 63) {
      gld_lds16(&Ks[buf ^ 1][tid * 16], Kbase + (size_t)(kb + 1) * 4096 + tid * 16);
      gld_lds16(&Vs[buf ^ 1][tid * 16], Vbase + (size_t)(kb + 1) * 4096 + tid * 16);
    }
    // S^T = K . Q^T : s[t][r] = S^T[k=16t+4g+r][q]
    f32x4 s[2];
#pragma unroll
    for (int t = 0; t < 2; t++) {
      const char* kr = &Ks[buf][kro + (u32)t * 2048];
      bf16x8 kf0 = *(const bf16x8*)(kr + (kin ^ ksw));
      bf16x8 kf1 = *(const bf16x8*)(kr + ((kin + 64) ^ ksw));
      f32x4 z = (f32x4){0.f, 0.f, 0.f, 0.f};
      s[t] = __builtin_amdgcn_mfma_f32_16x16x32_bf16(kf0, qf0, z, 0, 0, 0);
      s[t] = __builtin_amdgcn_mfma_f32_16x16x32_bf16(kf1, qf1, s[t], 0, 0, 0);
    }
    // online softmax over k: 7 in-lane fmax + 2 shfl (groups g hold disjoint k)
    float pm = fmaxf(fmaxf(fmaxf(s[0][0], s[0][1]), fmaxf(s[0][2], s[0][3])),
                     fmaxf(fmaxf(s[1][0], s[1][1]), fmaxf(s[1][2], s[1][3])));
    pm = fmaxf(pm, __shfl_xor(pm, 16));
    pm = fmaxf(pm, __shfl_xor(pm, 32));
    const float mn = fmaxf(m_, pm);
    const float corr = __expf(m_ - mn);
    float p[2][4];
    float rs = 0.f;
#pragma unroll
    for (int t = 0; t < 2; t++)
#pragma unroll
      for (int r = 0; r < 4; r++) {
        p[t][r] = __expf(s[t][r] - mn);
        rs += p[t][r];
      }
    rs += __shfl_xor(rs, 16);
    rs += __shfl_xor(rs, 32);
    ls = ls * corr + rs;
    m_ = mn;
#pragma unroll
    for (int c = 0; c < 4; c++) o_[c] *= corr;

    // PV: O^T[d][q] += V^T_frag x P^T_frag (16x16x16 f16), P stays in registers
#pragma unroll
    for (int t = 0; t < 2; t++) {
      f16x4 pf;
      pf.x = (_Float16)p[t][0];
      pf.y = (_Float16)p[t][1];
      pf.z = (_Float16)p[t][2];
      pf.w = (_Float16)p[t][3];
#pragma unroll
      for (int c = 0; c < 4; c++) {
        f16x4 vf = *(const f16x4*)&Vs[buf][(u32)(t * 4 + c) * 512 + (u32)l * 8];
        o_[c] = __builtin_amdgcn_mfma_f32_16x16x16f16(vf, pf, o_[c], 0, 0, 0);
      }
    }
    __syncthreads();
    buf ^= 1;
  }

  const float inv = 1.0f / ls;
  float* ob = out + ((size_t)b * 2048 + (size_t)(qt * 64 + w * 16 + q)) * 1024 + hh * 64;
#pragma unroll
  for (int c = 0; c < 4; c++) {
    f32x4 v = o_[c] * inv;
    *(f32x4*)(ob + c * 16 + g * 4) = v;
  }
}

extern "C" void kernel_launch(void* const* d_in, const int* in_sizes, int n_in,
                              void* d_out, int out_size, void* d_ws, size_t ws_size,
                              hipStream_t stream) {
  const float* x = (const float*)d_in[0];
  const float* text = (const float*)d_in[1];
  const float* Wq = (const float*)d_in[2];
  const float* bq = (const float*)d_in[3];
  const float* Wkv = (const float*)d_in[4];
  const float* bkv = (const float*)d_in[5];
  float* out = (float*)d_out;
  char* ws = (char*)d_ws;

  const size_t MiB = 1u << 20;
  u16* XB = (u16*)(ws + 0 * MiB);     // x bf16       [8192][1024]   16 MiB
  u16* TB = (u16*)(ws + 16 * MiB);    // text bf16    [8192][1024]   16 MiB
  u16* WQT = (u16*)(ws + 32 * MiB);   // Wq^T bf16    [1024][1024]    2 MiB
  u16* WKVT = (u16*)(ws + 34 * MiB);  // Wkv^T bf16   [2048][1024]    4 MiB
  u16* QG = (u16*)(ws + 38 * MiB);    // Q  bf16      [4][16][2048][64]
  u16* KG = (u16*)(ws + 54 * MiB);    // K  bf16      swizzled rows
  u16* VG = (u16*)(ws + 70 * MiB);    // V  f16       PV-fragment layout (end: 86 MiB)

  k_cast<<<2048, 256, 0, stream>>>(x, XB, 2097152);
  k_cast<<<2048, 256, 0, stream>>>(text, TB, 2097152);
  k_transpose_cast<<<dim3(32, 32), dim3(32, 8), 0, stream>>>(Wq, WQT, 1024, 1024);
  k_transpose_cast<<<dim3(64, 32), dim3(32, 8), 0, stream>>>(Wkv, WKVT, 1024, 2048);
  k_gemm<0><<<dim3(8, 64), 256, 0, stream>>>(XB, WQT, bq, QG, (u16*)nullptr);
  k_gemm<1><<<dim3(16, 64), 256, 0, stream>>>(TB, WKVT, bkv, KG, VG);
  k_attn<<<2048, 256, 0, stream>>>(QG, KG, VG, out);
}

// Round 4
// 244.983 us; speedup vs baseline: 1.6866x; 1.1275x over previous
//
#include <hip/hip_runtime.h>
#include <hip/hip_bf16.h>

// MQA cross-attention, B=4, LQ=LK=2048, D=1024, H=16, HD=64.
// Pipeline: cast(x,text)->bf16 ; transpose-cast(Wq,Wkv)->bf16 [N][K] ;
//   bf16 MFMA GEMM -> Q (scaled log2e/8), K (row-XOR-swizzled bf16), V (f16, PV-fragment layout) ;
//   flash attention: swapped QK^T (S^T in regs, log2 domain), KVBLK=64, defer-max online
//   softmax (2 shfl per 64 k), exp2, packed f16 cvt, PV via 16x16x16 f16 MFMA, P in regs.

typedef unsigned short u16;
typedef unsigned int u32;

typedef __attribute__((ext_vector_type(8))) __bf16 bf16x8;
typedef __attribute__((ext_vector_type(2))) _Float16 f16x2;
typedef __attribute__((ext_vector_type(4))) _Float16 f16x4;
typedef __attribute__((ext_vector_type(4))) float f32x4;
typedef __attribute__((ext_vector_type(4))) float f4;
typedef __attribute__((ext_vector_type(4))) unsigned short u16x4;

#define DEVI __device__ __forceinline__

DEVI u16 f2b(float f) {  // fp32 -> bf16 RNE (finite inputs)
  u32 u = __float_as_uint(f);
  return (u16)((u + 0x7fffu + ((u >> 16) & 1u)) >> 16);
}

DEVI u16 f2h(float f) {  // fp32 -> f16 bits
  _Float16 h = (_Float16)f;
  return __builtin_bit_cast(u16, h);
}

DEVI f16x2 pk_f16(float a, float b) {  // packed f32->f16 (RTZ), one VALU op
  return __builtin_bit_cast(f16x2, __builtin_amdgcn_cvt_pkrtz(a, b));
}

DEVI void gld_lds16(void* lds, const void* g) {
  // async global->LDS, 16B/lane; dest is wave-uniform base + lane*16
  __builtin_amdgcn_global_load_lds(
      (const __attribute__((address_space(1))) u32*)g,
      (__attribute__((address_space(3))) u32*)lds, 16, 0, 0);
}

// ---------------- cast f32 -> bf16 ----------------
__global__ void k_cast(const float* __restrict__ in, u16* __restrict__ out, int n4) {
  int i = blockIdx.x * blockDim.x + threadIdx.x;
  int stride = gridDim.x * blockDim.x;
  for (; i < n4; i += stride) {
    f4 v = ((const f4*)in)[i];
    u16x4 o;
    o.x = f2b(v.x); o.y = f2b(v.y); o.z = f2b(v.z); o.w = f2b(v.w);
    ((u16x4*)out)[i] = o;
  }
}

// -------- transpose + cast: in [K][N] f32 -> out [N][K] bf16 --------
__global__ void k_transpose_cast(const float* __restrict__ in, u16* __restrict__ out,
                                 int K, int N) {
  __shared__ float tile[32][33];
  int n0 = blockIdx.x * 32, k0 = blockIdx.y * 32;
  int tx = threadIdx.x, ty = threadIdx.y;  // block (32,8)
#pragma unroll
  for (int j = 0; j < 32; j += 8)
    tile[ty + j][tx] = in[(size_t)(k0 + ty + j) * N + n0 + tx];
  __syncthreads();
#pragma unroll
  for (int j = 0; j < 32; j += 8)
    out[(size_t)(n0 + ty + j) * K + k0 + tx] = f2b(tile[tx][ty + j]);
}

// ---------------- bf16 GEMM: C[M,N] = A[M,1024] @ Bt[N,1024]^T + bias ----------------
// EPI 0: Q epilogue   -> out0 = QG [b][h][2048][64] bf16, value*(log2e/8)
// EPI 1: KV epilogue  -> n<1024: K -> out0 = KG [b][h][2048] rows of 128B, XOR-swizzled
//                        n>=1024: V -> out1 = VG f16, PV-fragment blocked layout
template <int EPI>
__global__ __launch_bounds__(256) void k_gemm(
    const u16* __restrict__ A, const u16* __restrict__ Bt,
    const float* __restrict__ bias, u16* __restrict__ out0, u16* __restrict__ out1) {
  __shared__ alignas(16) char As[2][8192];
  __shared__ alignas(16) char Bs[2][8192];
  const int tid = threadIdx.x;
  const int w = tid >> 6, l = tid & 63;
  const int wr = w >> 1, wc = w & 1;
  const int m0 = blockIdx.y << 7, n0 = blockIdx.x << 7;

  // staging: LDS linear [128 rows][64B], source pre-XOR-swizzled (^((row&3)<<4))
  u32 soff[2], doff[2];
#pragma unroll
  for (int i = 0; i < 2; i++) {
    u32 o = (u32)(i * 4096 + tid * 16);
    u32 row = o >> 6;
    soff[i] = row * 2048 + ((o & 63) ^ ((row & 3) << 4));
    doff[i] = o;
  }
  const char* Aorig = (const char*)A + (size_t)m0 * 2048;
  const char* Borig = (const char*)Bt + (size_t)n0 * 2048;

  f32x4 acc[4][4];
#pragma unroll
  for (int i = 0; i < 4; i++)
#pragma unroll
    for (int j = 0; j < 4; j++) acc[i][j] = (f32x4){0.f, 0.f, 0.f, 0.f};

  const u32 co = (u32)(((l >> 4) ^ (l & 3)) << 4);  // swizzled k-chunk
  const u32 arow = (u32)(wr * 64 + (l & 15)) * 64;
  const u32 brow = (u32)(wc * 64 + (l & 15)) * 64;

#pragma unroll
  for (int i = 0; i < 2; i++) {
    gld_lds16(&As[0][doff[i]], Aorig + soff[i]);
    gld_lds16(&Bs[0][doff[i]], Borig + soff[i]);
  }
  __syncthreads();
  int buf = 0;
  for (int kt = 0; kt < 32; kt++) {
    if (kt < 31) {
#pragma unroll
      for (int i = 0; i < 2; i++) {
        gld_lds16(&As[buf ^ 1][doff[i]], Aorig + (u32)(kt + 1) * 64 + soff[i]);
        gld_lds16(&Bs[buf ^ 1][doff[i]], Borig + (u32)(kt + 1) * 64 + soff[i]);
      }
    }
    bf16x8 af[4], bfr[4];
#pragma unroll
    for (int t = 0; t < 4; t++) {
      af[t] = *(const bf16x8*)&As[buf][arow + (u32)t * 1024 + co];
      bfr[t] = *(const bf16x8*)&Bs[buf][brow + (u32)t * 1024 + co];
    }
#pragma unroll
    for (int i = 0; i < 4; i++)
#pragma unroll
      for (int j = 0; j < 4; j++)
        acc[i][j] = __builtin_amdgcn_mfma_f32_16x16x32_bf16(af[i], bfr[j], acc[i][j], 0, 0, 0);
    __syncthreads();
    buf ^= 1;
  }

  // epilogue: C row = m0+wr*64+i*16+4*(l>>4)+r ; col = n0+wc*64+j*16+(l&15)
#pragma unroll
  for (int i = 0; i < 4; i++) {
    const int mbase = m0 + wr * 64 + i * 16 + ((l >> 4) << 2);
    const int bb = mbase >> 11;      // batch
    const int mrow = mbase & 2047;   // q or lk (mrow%4==0)
#pragma unroll
    for (int j = 0; j < 4; j++) {
      const int n = n0 + wc * 64 + j * 16 + (l & 15);
      const float bv = bias[n];
      if (EPI == 0) {
        // Q scaled by (1/8)*log2(e) so attention works in exp2 domain
        const int h = n >> 6, hd = n & 63;
        u16* dst = out0 + ((((size_t)bb * 16 + h) * 2048 + mrow) << 6) + hd;
#pragma unroll
        for (int r = 0; r < 4; r++)
          dst[(size_t)r << 6] = f2b((acc[i][j][r] + bv) * 0.18033688011112042f);
      } else if (n < 1024) {  // K: rows of 128B, in-row byte ^= ((lk&7)<<4)
        const int h = n >> 6, d = n & 63;
        char* base = (char*)out0 + ((((size_t)bb * 16 + h) * 2048 + mrow) << 7);
#pragma unroll
        for (int r = 0; r < 4; r++) {
          u32 off = (u32)r * 128 + (((u32)d * 2) ^ (((u32)(mrow + r) & 7) << 4));
          *(u16*)(base + off) = f2b(acc[i][j][r] + bv);
        }
      } else {
        // V (f16): PV-fragment layout. Element V[lk][hd] lives at byte
        //   blk(lk>>5)*4096 + ((lk>>4)&1)*2048 + (hd>>4)*512 + ((lk>>2)&3)*128 + (hd&15)*8 + (lk&3)*2
        const int nn = n - 1024;
        const int h = nn >> 6, hd = nn & 63;
        u16x4 pk;
        pk.x = f2h(acc[i][j][0] + bv);
        pk.y = f2h(acc[i][j][1] + bv);
        pk.z = f2h(acc[i][j][2] + bv);
        pk.w = f2h(acc[i][j][3] + bv);
        char* base = (char*)out1 + (((size_t)bb * 16 + h) << 18);
        u32 off = ((u32)(mrow >> 5) << 12) + (((u32)(mrow >> 4) & 1) << 11) +
                  ((u32)(hd >> 4) << 9) + (((u32)(mrow >> 2) & 3) << 7) +
                  ((u32)(hd & 15) << 3);
        *(u16x4*)(base + off) = pk;
      }
    }
  }
}

// ---------------- flash attention ----------------
// grid = B*H*(LQ/64); block 256 = 4 waves, wave w owns q rows w*16..w*16+15.
// Swapped QK^T: S^T[k][q] in regs (q = lane&15), log2 domain; KVBLK=64 (one softmax
// pass / 64 k, 2+2 shfl); defer-max rescale (THR=10); P stays in regs (pkrtz ->
// f16 B-frag); O^T += mfma_16x16x16_f16(V^T_frag, P^T_frag).
__global__ __launch_bounds__(256) void k_attn(
    const u16* __restrict__ QG, const u16* __restrict__ KG, const u16* __restrict__ VG,
    float* __restrict__ out) {
  __shared__ alignas(16) char Ks[2][8192];
  __shared__ alignas(16) char Vs[2][8192];
  const int tid = threadIdx.x, w = tid >> 6, l = tid & 63;
  const int g = l >> 4, q = l & 15;
  const int qt = blockIdx.x & 31;
  const int hh = (blockIdx.x >> 5) & 15;
  const int b = blockIdx.x >> 9;
  const size_t bh = (size_t)b * 16 + hh;

  // Q B-frags in regs: lane holds Q[q][d=8g+e] (+32 for half 1); Q pre-scaled log2e/8
  const u16* Qp = QG + ((bh * 2048 + (size_t)(qt * 64 + w * 16 + q)) << 6) + (g << 3);
  const bf16x8 qf0 = *(const bf16x8*)Qp;
  const bf16x8 qf1 = *(const bf16x8*)(Qp + 32);

  const char* Kbase = (const char*)KG + (bh << 18);  // 2048 rows * 128B
  const char* Vbase = (const char*)VG + (bh << 18);  // f16 fragment layout, 8KB / 64 k

  float m_ = -__builtin_inff(), ls = 0.f;
  f32x4 o_[4];  // o_[c][r] = O^T[d=16c+4g+r][q]
#pragma unroll
  for (int c = 0; c < 4; c++) o_[c] = (f32x4){0.f, 0.f, 0.f, 0.f};

  gld_lds16(&Ks[0][tid * 16], Kbase + tid * 16);
  gld_lds16(&Ks[0][4096 + tid * 16], Kbase + 4096 + tid * 16);
  gld_lds16(&Vs[0][tid * 16], Vbase + tid * 16);
  gld_lds16(&Vs[0][4096 + tid * 16], Vbase + 4096 + tid * 16);
  __syncthreads();

  int buf = 0;
  const u32 ksw = ((u32)(l & 7)) << 4;  // K row swizzle key (row&7 == l&7)
  const u32 kro = ((u32)q) << 7;        // K row * 128B
  const u32 kin = ((u32)g) << 4;        // d-chunk byte

  for (int kb = 0; kb < 32; kb++) {
    if (kb < 31) {
      const char* kp = Kbase + (size_t)(kb + 1) * 8192;
      const char* vp = Vbase + (size_t)(kb + 1) * 8192;
      gld_lds16(&Ks[buf ^ 1][tid * 16], kp + tid * 16);
      gld_lds16(&Ks[buf ^ 1][4096 + tid * 16], kp + 4096 + tid * 16);
      gld_lds16(&Vs[buf ^ 1][tid * 16], vp + tid * 16);
      gld_lds16(&Vs[buf ^ 1][4096 + tid * 16], vp + 4096 + tid * 16);
    }
    // S^T = K . Q^T : s[t][r] = S^T[k=16t+4g+r][q], log2 domain
    f32x4 s[4];
    __builtin_amdgcn_s_setprio(1);
#pragma unroll
    for (int t = 0; t < 4; t++) {
      const char* kr = &Ks[buf][kro + (u32)t * 2048];
      bf16x8 kf0 = *(const bf16x8*)(kr + (kin ^ ksw));
      bf16x8 kf1 = *(const bf16x8*)(kr + ((kin + 64) ^ ksw));
      f32x4 z = (f32x4){0.f, 0.f, 0.f, 0.f};
      s[t] = __builtin_amdgcn_mfma_f32_16x16x32_bf16(kf0, qf0, z, 0, 0, 0);
      s[t] = __builtin_amdgcn_mfma_f32_16x16x32_bf16(kf1, qf1, s[t], 0, 0, 0);
    }
    __builtin_amdgcn_s_setprio(0);
    // one softmax pass over 16 in-lane k values + 2 shfl
    float pa = fmaxf(fmaxf(s[0][0], s[0][1]), fmaxf(s[0][2], s[0][3]));
    float pb = fmaxf(fmaxf(s[1][0], s[1][1]), fmaxf(s[1][2], s[1][3]));
    float pc = fmaxf(fmaxf(s[2][0], s[2][1]), fmaxf(s[2][2], s[2][3]));
    float pd = fmaxf(fmaxf(s[3][0], s[3][1]), fmaxf(s[3][2], s[3][3]));
    float pm = fmaxf(fmaxf(pa, pb), fmaxf(pc, pd));
    pm = fmaxf(pm, __shfl_xor(pm, 16));
    pm = fmaxf(pm, __shfl_xor(pm, 32));
    // defer-max: rescale only when max grew by > 10 (P bounded by 2^10, f16-safe)
    if (!__all(pm - m_ <= 10.f)) {
      const float mn = fmaxf(m_, pm);
      const float corr = __builtin_amdgcn_exp2f(m_ - mn);
      ls *= corr;
#pragma unroll
      for (int c = 0; c < 4; c++) o_[c] *= corr;
      m_ = mn;
    }
    float p[4][4];
    float r0 = 0.f, r1 = 0.f;
#pragma unroll
    for (int t = 0; t < 4; t++) {
      p[t][0] = __builtin_amdgcn_exp2f(s[t][0] - m_);
      p[t][1] = __builtin_amdgcn_exp2f(s[t][1] - m_);
      p[t][2] = __builtin_amdgcn_exp2f(s[t][2] - m_);
      p[t][3] = __builtin_amdgcn_exp2f(s[t][3] - m_);
      r0 += p[t][0] + p[t][2];
      r1 += p[t][1] + p[t][3];
    }
    float rs = r0 + r1;
    rs += __shfl_xor(rs, 16);
    rs += __shfl_xor(rs, 32);
    ls += rs;

    // PV: O^T[d][q] += V^T_frag x P^T_frag (16x16x16 f16), P in registers
    __builtin_amdgcn_s_setprio(1);
#pragma unroll
    for (int t = 0; t < 4; t++) {
      f16x2 lo = pk_f16(p[t][0], p[t][1]);
      f16x2 hi = pk_f16(p[t][2], p[t][3]);
      f16x4 pf;
      pf.x = lo.x; pf.y = lo.y; pf.z = hi.x; pf.w = hi.y;
      const u32 vb = ((u32)(t >> 1) << 12) + ((u32)(t & 1) << 11);
#pragma unroll
      for (int c = 0; c < 4; c++) {
        f16x4 vf = *(const f16x4*)&Vs[buf][vb + (u32)c * 512 + (u32)l * 8];
        o_[c] = __builtin_amdgcn_mfma_f32_16x16x16f16(vf, pf, o_[c], 0, 0, 0);
      }
    }
    __builtin_amdgcn_s_setprio(0);
    __syncthreads();
    buf ^= 1;
  }

  const float inv = 1.0f / ls;
  float* ob = out + ((size_t)b * 2048 + (size_t)(qt * 64 + w * 16 + q)) * 1024 + hh * 64;
#pragma unroll
  for (int c = 0; c < 4; c++) {
    f32x4 v = o_[c] * inv;
    *(f32x4*)(ob + c * 16 + g * 4) = v;
  }
}

extern "C" void kernel_launch(void* const* d_in, const int* in_sizes, int n_in,
                              void* d_out, int out_size, void* d_ws, size_t ws_size,
                              hipStream_t stream) {
  const float* x = (const float*)d_in[0];
  const float* text = (const float*)d_in[1];
  const float* Wq = (const float*)d_in[2];
  const float* bq = (const float*)d_in[3];
  const float* Wkv = (const float*)d_in[4];
  const float* bkv = (const float*)d_in[5];
  float* out = (float*)d_out;
  char* ws = (char*)d_ws;

  const size_t MiB = 1u << 20;
  u16* XB = (u16*)(ws + 0 * MiB);     // x bf16       [8192][1024]   16 MiB
  u16* TB = (u16*)(ws + 16 * MiB);    // text bf16    [8192][1024]   16 MiB
  u16* WQT = (u16*)(ws + 32 * MiB);   // Wq^T bf16    [1024][1024]    2 MiB
  u16* WKVT = (u16*)(ws + 34 * MiB);  // Wkv^T bf16   [2048][1024]    4 MiB
  u16* QG = (u16*)(ws + 38 * MiB);    // Q  bf16      [4][16][2048][64]
  u16* KG = (u16*)(ws + 54 * MiB);    // K  bf16      swizzled rows
  u16* VG = (u16*)(ws + 70 * MiB);    // V  f16       PV-fragment layout (end: 86 MiB)

  k_cast<<<2048, 256, 0, stream>>>(x, XB, 2097152);
  k_cast<<<2048, 256, 0, stream>>>(text, TB, 2097152);
  k_transpose_cast<<<dim3(32, 32), dim3(32, 8), 0, stream>>>(Wq, WQT, 1024, 1024);
  k_transpose_cast<<<dim3(64, 32), dim3(32, 8), 0, stream>>>(Wkv, WKVT, 1024, 2048);
  k_gemm<0><<<dim3(8, 64), 256, 0, stream>>>(XB, WQT, bq, QG, (u16*)nullptr);
  k_gemm<1><<<dim3(16, 64), 256, 0, stream>>>(TB, WKVT, bkv, KG, VG);
  k_attn<<<2048, 256, 0, stream>>>(QG, KG, VG, out);
}

// Round 5
// 239.717 us; speedup vs baseline: 1.7237x; 1.0220x over previous
//
#include <hip/hip_runtime.h>
#include <hip/hip_bf16.h>

// MQA cross-attention, B=4, LQ=LK=2048, D=1024, H=16, HD=64.
// Pipeline: cast(x,text)->bf16 ; transpose-cast(Wq,Wkv)->bf16 [N][K] ;
//   bf16 MFMA GEMM -> Q (scaled log2e/8), K (row-XOR-swizzled bf16), V (f16, PV-fragment layout) ;
//   flash attention: swapped QK^T, 2 q-groups per wave (K/V frags reused), KVBLK=64,
//   defer-max softmax, exp2 domain, lane-local ls (end reduce), PV via 16x16x16 f16 MFMA.

typedef unsigned short u16;
typedef unsigned int u32;

typedef __attribute__((ext_vector_type(8))) __bf16 bf16x8;
typedef __attribute__((ext_vector_type(2))) _Float16 f16x2;
typedef __attribute__((ext_vector_type(4))) _Float16 f16x4;
typedef __attribute__((ext_vector_type(4))) float f32x4;
typedef __attribute__((ext_vector_type(4))) float f4;
typedef __attribute__((ext_vector_type(4))) unsigned short u16x4;

#define DEVI __device__ __forceinline__

DEVI u16 f2b(float f) {  // fp32 -> bf16 RNE (finite inputs)
  u32 u = __float_as_uint(f);
  return (u16)((u + 0x7fffu + ((u >> 16) & 1u)) >> 16);
}

DEVI u16 f2h(float f) {  // fp32 -> f16 bits
  _Float16 h = (_Float16)f;
  return __builtin_bit_cast(u16, h);
}

DEVI f16x2 pk_f16(float a, float b) {  // packed f32->f16 (RTZ), one VALU op
  return __builtin_bit_cast(f16x2, __builtin_amdgcn_cvt_pkrtz(a, b));
}

DEVI void gld_lds16(void* lds, const void* g) {
  // async global->LDS, 16B/lane; dest is wave-uniform base + lane*16
  __builtin_amdgcn_global_load_lds(
      (const __attribute__((address_space(1))) u32*)g,
      (__attribute__((address_space(3))) u32*)lds, 16, 0, 0);
}

// ---------------- cast f32 -> bf16 ----------------
__global__ void k_cast(const float* __restrict__ in, u16* __restrict__ out, int n4) {
  int i = blockIdx.x * blockDim.x + threadIdx.x;
  int stride = gridDim.x * blockDim.x;
  for (; i < n4; i += stride) {
    f4 v = ((const f4*)in)[i];
    u16x4 o;
    o.x = f2b(v.x); o.y = f2b(v.y); o.z = f2b(v.z); o.w = f2b(v.w);
    ((u16x4*)out)[i] = o;
  }
}

// -------- transpose + cast: in [K][N] f32 -> out [N][K] bf16 --------
__global__ void k_transpose_cast(const float* __restrict__ in, u16* __restrict__ out,
                                 int K, int N) {
  __shared__ float tile[32][33];
  int n0 = blockIdx.x * 32, k0 = blockIdx.y * 32;
  int tx = threadIdx.x, ty = threadIdx.y;  // block (32,8)
#pragma unroll
  for (int j = 0; j < 32; j += 8)
    tile[ty + j][tx] = in[(size_t)(k0 + ty + j) * N + n0 + tx];
  __syncthreads();
#pragma unroll
  for (int j = 0; j < 32; j += 8)
    out[(size_t)(n0 + ty + j) * K + k0 + tx] = f2b(tile[tx][ty + j]);
}

// ---------------- bf16 GEMM: C[M,N] = A[M,1024] @ Bt[N,1024]^T + bias ----------------
// EPI 0: Q epilogue   -> out0 = QG [b][h][2048][64] bf16, value*(log2e/8)
// EPI 1: KV epilogue  -> n<1024: K -> out0 = KG [b][h][2048] rows of 128B, XOR-swizzled
//                        n>=1024: V -> out1 = VG f16, PV-fragment blocked layout
template <int EPI>
__global__ __launch_bounds__(256) void k_gemm(
    const u16* __restrict__ A, const u16* __restrict__ Bt,
    const float* __restrict__ bias, u16* __restrict__ out0, u16* __restrict__ out1) {
  __shared__ alignas(16) char As[2][8192];
  __shared__ alignas(16) char Bs[2][8192];
  const int tid = threadIdx.x;
  const int w = tid >> 6, l = tid & 63;
  const int wr = w >> 1, wc = w & 1;
  const int m0 = blockIdx.y << 7, n0 = blockIdx.x << 7;

  // staging: LDS linear [128 rows][64B], source pre-XOR-swizzled (^((row&3)<<4))
  u32 soff[2], doff[2];
#pragma unroll
  for (int i = 0; i < 2; i++) {
    u32 o = (u32)(i * 4096 + tid * 16);
    u32 row = o >> 6;
    soff[i] = row * 2048 + ((o & 63) ^ ((row & 3) << 4));
    doff[i] = o;
  }
  const char* Aorig = (const char*)A + (size_t)m0 * 2048;
  const char* Borig = (const char*)Bt + (size_t)n0 * 2048;

  f32x4 acc[4][4];
#pragma unroll
  for (int i = 0; i < 4; i++)
#pragma unroll
    for (int j = 0; j < 4; j++) acc[i][j] = (f32x4){0.f, 0.f, 0.f, 0.f};

  const u32 co = (u32)(((l >> 4) ^ (l & 3)) << 4);  // swizzled k-chunk
  const u32 arow = (u32)(wr * 64 + (l & 15)) * 64;
  const u32 brow = (u32)(wc * 64 + (l & 15)) * 64;

#pragma unroll
  for (int i = 0; i < 2; i++) {
    gld_lds16(&As[0][doff[i]], Aorig + soff[i]);
    gld_lds16(&Bs[0][doff[i]], Borig + soff[i]);
  }
  __syncthreads();
  int buf = 0;
  for (int kt = 0; kt < 32; kt++) {
    if (kt < 31) {
#pragma unroll
      for (int i = 0; i < 2; i++) {
        gld_lds16(&As[buf ^ 1][doff[i]], Aorig + (u32)(kt + 1) * 64 + soff[i]);
        gld_lds16(&Bs[buf ^ 1][doff[i]], Borig + (u32)(kt + 1) * 64 + soff[i]);
      }
    }
    bf16x8 af[4], bfr[4];
#pragma unroll
    for (int t = 0; t < 4; t++) {
      af[t] = *(const bf16x8*)&As[buf][arow + (u32)t * 1024 + co];
      bfr[t] = *(const bf16x8*)&Bs[buf][brow + (u32)t * 1024 + co];
    }
#pragma unroll
    for (int i = 0; i < 4; i++)
#pragma unroll
      for (int j = 0; j < 4; j++)
        acc[i][j] = __builtin_amdgcn_mfma_f32_16x16x32_bf16(af[i], bfr[j], acc[i][j], 0, 0, 0);
    __syncthreads();
    buf ^= 1;
  }

  // epilogue: C row = m0+wr*64+i*16+4*(l>>4)+r ; col = n0+wc*64+j*16+(l&15)
#pragma unroll
  for (int i = 0; i < 4; i++) {
    const int mbase = m0 + wr * 64 + i * 16 + ((l >> 4) << 2);
    const int bb = mbase >> 11;      // batch
    const int mrow = mbase & 2047;   // q or lk (mrow%4==0)
#pragma unroll
    for (int j = 0; j < 4; j++) {
      const int n = n0 + wc * 64 + j * 16 + (l & 15);
      const float bv = bias[n];
      if (EPI == 0) {
        // Q scaled by (1/8)*log2(e) so attention works in exp2 domain
        const int h = n >> 6, hd = n & 63;
        u16* dst = out0 + ((((size_t)bb * 16 + h) * 2048 + mrow) << 6) + hd;
#pragma unroll
        for (int r = 0; r < 4; r++)
          dst[(size_t)r << 6] = f2b((acc[i][j][r] + bv) * 0.18033688011112042f);
      } else if (n < 1024) {  // K: rows of 128B, in-row byte ^= ((lk&7)<<4)
        const int h = n >> 6, d = n & 63;
        char* base = (char*)out0 + ((((size_t)bb * 16 + h) * 2048 + mrow) << 7);
#pragma unroll
        for (int r = 0; r < 4; r++) {
          u32 off = (u32)r * 128 + (((u32)d * 2) ^ (((u32)(mrow + r) & 7) << 4));
          *(u16*)(base + off) = f2b(acc[i][j][r] + bv);
        }
      } else {
        // V (f16): PV-fragment layout. Element V[lk][hd] lives at byte
        //   blk(lk>>5)*4096 + ((lk>>4)&1)*2048 + (hd>>4)*512 + ((lk>>2)&3)*128 + (hd&15)*8 + (lk&3)*2
        const int nn = n - 1024;
        const int h = nn >> 6, hd = nn & 63;
        u16x4 pk;
        pk.x = f2h(acc[i][j][0] + bv);
        pk.y = f2h(acc[i][j][1] + bv);
        pk.z = f2h(acc[i][j][2] + bv);
        pk.w = f2h(acc[i][j][3] + bv);
        char* base = (char*)out1 + (((size_t)bb * 16 + h) << 18);
        u32 off = ((u32)(mrow >> 5) << 12) + (((u32)(mrow >> 4) & 1) << 11) +
                  ((u32)(hd >> 4) << 9) + (((u32)(mrow >> 2) & 3) << 7) +
                  ((u32)(hd & 15) << 3);
        *(u16x4*)(base + off) = pk;
      }
    }
  }
}

// ---------------- flash attention ----------------
// grid = B*H*(LQ/128); block 256 = 4 waves. Wave w owns TWO q-groups:
//   A: rows qt*128 + w*16 + q ; B: rows qt*128 + 64 + w*16 + q   (q = lane&15)
// K/V register fragments are read from LDS once and reused for both groups.
// Swapped QK^T (S^T in regs, log2 domain); defer-max rescale (THR=10);
// lane-local ls (cross-lane reduce once at end); PV via 16x16x16 f16 MFMA.
__global__ __launch_bounds__(256) void k_attn(
    const u16* __restrict__ QG, const u16* __restrict__ KG, const u16* __restrict__ VG,
    float* __restrict__ out) {
  __shared__ alignas(16) char Ks[2][8192];
  __shared__ alignas(16) char Vs[2][8192];
  const int tid = threadIdx.x, w = tid >> 6, l = tid & 63;
  const int g = l >> 4, q = l & 15;
  const int qt = blockIdx.x & 15;
  const int hh = (blockIdx.x >> 4) & 15;
  const int b = blockIdx.x >> 8;
  const size_t bh = (size_t)b * 16 + hh;

  const int qrowA = qt * 128 + w * 16 + q;
  const int qrowB = qrowA + 64;

  // Q B-frags in regs: lane holds Q[q][d=8g+e] (+32 for half 1); Q pre-scaled log2e/8
  const u16* QpA = QG + ((bh * 2048 + (size_t)qrowA) << 6) + (g << 3);
  const u16* QpB = QG + ((bh * 2048 + (size_t)qrowB) << 6) + (g << 3);
  const bf16x8 qf0a = *(const bf16x8*)QpA;
  const bf16x8 qf1a = *(const bf16x8*)(QpA + 32);
  const bf16x8 qf0b = *(const bf16x8*)QpB;
  const bf16x8 qf1b = *(const bf16x8*)(QpB + 32);

  const char* Kbase = (const char*)KG + (bh << 18);  // 2048 rows * 128B
  const char* Vbase = (const char*)VG + (bh << 18);  // f16 fragment layout, 8KB / 64 k

  float m_a = -__builtin_inff(), ls_a = 0.f;
  float m_b = -__builtin_inff(), ls_b = 0.f;
  f32x4 oa[4], ob4[4];  // [c][r] = O^T[d=16c+4g+r][q]
#pragma unroll
  for (int c = 0; c < 4; c++) {
    oa[c] = (f32x4){0.f, 0.f, 0.f, 0.f};
    ob4[c] = (f32x4){0.f, 0.f, 0.f, 0.f};
  }

  gld_lds16(&Ks[0][tid * 16], Kbase + tid * 16);
  gld_lds16(&Ks[0][4096 + tid * 16], Kbase + 4096 + tid * 16);
  gld_lds16(&Vs[0][tid * 16], Vbase + tid * 16);
  gld_lds16(&Vs[0][4096 + tid * 16], Vbase + 4096 + tid * 16);
  __syncthreads();

  int buf = 0;
  const u32 ksw = ((u32)(l & 7)) << 4;  // K row swizzle key (row&7 == l&7)
  const u32 kro = ((u32)q) << 7;        // K row * 128B
  const u32 kin = ((u32)g) << 4;        // d-chunk byte

  for (int kb = 0; kb < 32; kb++) {
    if (kb < 31) {
      const char* kp = Kbase + (size_t)(kb + 1) * 8192;
      const char* vp = Vbase + (size_t)(kb + 1) * 8192;
      gld_lds16(&Ks[buf ^ 1][tid * 16], kp + tid * 16);
      gld_lds16(&Ks[buf ^ 1][4096 + tid * 16], kp + 4096 + tid * 16);
      gld_lds16(&Vs[buf ^ 1][tid * 16], vp + tid * 16);
      gld_lds16(&Vs[buf ^ 1][4096 + tid * 16], vp + 4096 + tid * 16);
    }
    // S^T = K . Q^T : s*[t][r] = S^T[k=16t+4g+r][q], log2 domain; K frags reused A/B
    f32x4 sa[4], sb[4];
    __builtin_amdgcn_s_setprio(1);
#pragma unroll
    for (int t = 0; t < 4; t++) {
      const char* kr = &Ks[buf][kro + (u32)t * 2048];
      bf16x8 kf0 = *(const bf16x8*)(kr + (kin ^ ksw));
      bf16x8 kf1 = *(const bf16x8*)(kr + ((kin + 64) ^ ksw));
      f32x4 z = (f32x4){0.f, 0.f, 0.f, 0.f};
      sa[t] = __builtin_amdgcn_mfma_f32_16x16x32_bf16(kf0, qf0a, z, 0, 0, 0);
      sa[t] = __builtin_amdgcn_mfma_f32_16x16x32_bf16(kf1, qf1a, sa[t], 0, 0, 0);
      sb[t] = __builtin_amdgcn_mfma_f32_16x16x32_bf16(kf0, qf0b, z, 0, 0, 0);
      sb[t] = __builtin_amdgcn_mfma_f32_16x16x32_bf16(kf1, qf1b, sb[t], 0, 0, 0);
    }
    __builtin_amdgcn_s_setprio(0);

    // ---- softmax group A ----
    float pa0 = fmaxf(fmaxf(sa[0][0], sa[0][1]), fmaxf(sa[0][2], sa[0][3]));
    float pa1 = fmaxf(fmaxf(sa[1][0], sa[1][1]), fmaxf(sa[1][2], sa[1][3]));
    float pa2 = fmaxf(fmaxf(sa[2][0], sa[2][1]), fmaxf(sa[2][2], sa[2][3]));
    float pa3 = fmaxf(fmaxf(sa[3][0], sa[3][1]), fmaxf(sa[3][2], sa[3][3]));
    float pmA = fmaxf(fmaxf(pa0, pa1), fmaxf(pa2, pa3));
    pmA = fmaxf(pmA, __shfl_xor(pmA, 16));
    pmA = fmaxf(pmA, __shfl_xor(pmA, 32));
    if (!__all(pmA - m_a <= 10.f)) {
      const float mn = fmaxf(m_a, pmA);
      const float corr = __builtin_amdgcn_exp2f(m_a - mn);
      ls_a *= corr;
#pragma unroll
      for (int c = 0; c < 4; c++) oa[c] *= corr;
      m_a = mn;
    }
    float pA[4][4];
#pragma unroll
    for (int t = 0; t < 4; t++)
#pragma unroll
      for (int r = 0; r < 4; r++) {
        pA[t][r] = __builtin_amdgcn_exp2f(sa[t][r] - m_a);
        ls_a += pA[t][r];  // lane-local partial; cross-lane reduce at end
      }

    // ---- softmax group B ----
    float pb0 = fmaxf(fmaxf(sb[0][0], sb[0][1]), fmaxf(sb[0][2], sb[0][3]));
    float pb1 = fmaxf(fmaxf(sb[1][0], sb[1][1]), fmaxf(sb[1][2], sb[1][3]));
    float pb2 = fmaxf(fmaxf(sb[2][0], sb[2][1]), fmaxf(sb[2][2], sb[2][3]));
    float pb3 = fmaxf(fmaxf(sb[3][0], sb[3][1]), fmaxf(sb[3][2], sb[3][3]));
    float pmB = fmaxf(fmaxf(pb0, pb1), fmaxf(pb2, pb3));
    pmB = fmaxf(pmB, __shfl_xor(pmB, 16));
    pmB = fmaxf(pmB, __shfl_xor(pmB, 32));
    if (!__all(pmB - m_b <= 10.f)) {
      const float mn = fmaxf(m_b, pmB);
      const float corr = __builtin_amdgcn_exp2f(m_b - mn);
      ls_b *= corr;
#pragma unroll
      for (int c = 0; c < 4; c++) ob4[c] *= corr;
      m_b = mn;
    }
    float pB[4][4];
#pragma unroll
    for (int t = 0; t < 4; t++)
#pragma unroll
      for (int r = 0; r < 4; r++) {
        pB[t][r] = __builtin_amdgcn_exp2f(sb[t][r] - m_b);
        ls_b += pB[t][r];
      }

    // PV: O^T[d][q] += V^T_frag x P^T_frag (16x16x16 f16); V frags reused A/B
    __builtin_amdgcn_s_setprio(1);
#pragma unroll
    for (int t = 0; t < 4; t++) {
      f16x2 loA = pk_f16(pA[t][0], pA[t][1]);
      f16x2 hiA = pk_f16(pA[t][2], pA[t][3]);
      f16x4 pfa;
      pfa.x = loA.x; pfa.y = loA.y; pfa.z = hiA.x; pfa.w = hiA.y;
      f16x2 loB = pk_f16(pB[t][0], pB[t][1]);
      f16x2 hiB = pk_f16(pB[t][2], pB[t][3]);
      f16x4 pfb;
      pfb.x = loB.x; pfb.y = loB.y; pfb.z = hiB.x; pfb.w = hiB.y;
      const u32 vb = ((u32)(t >> 1) << 12) + ((u32)(t & 1) << 11);
#pragma unroll
      for (int c = 0; c < 4; c++) {
        f16x4 vf = *(const f16x4*)&Vs[buf][vb + (u32)c * 512 + (u32)l * 8];
        oa[c] = __builtin_amdgcn_mfma_f32_16x16x16f16(vf, pfa, oa[c], 0, 0, 0);
        ob4[c] = __builtin_amdgcn_mfma_f32_16x16x16f16(vf, pfb, ob4[c], 0, 0, 0);
      }
    }
    __builtin_amdgcn_s_setprio(0);
    __syncthreads();
    buf ^= 1;
  }

  // final cross-lane ls reduce (deferred out of the loop)
  ls_a += __shfl_xor(ls_a, 16);
  ls_a += __shfl_xor(ls_a, 32);
  ls_b += __shfl_xor(ls_b, 16);
  ls_b += __shfl_xor(ls_b, 32);
  const float invA = 1.0f / ls_a;
  const float invB = 1.0f / ls_b;
  float* obA = out + ((size_t)b * 2048 + (size_t)qrowA) * 1024 + hh * 64;
  float* obB = out + ((size_t)b * 2048 + (size_t)qrowB) * 1024 + hh * 64;
#pragma unroll
  for (int c = 0; c < 4; c++) {
    f32x4 va = oa[c] * invA;
    f32x4 vb2 = ob4[c] * invB;
    *(f32x4*)(obA + c * 16 + g * 4) = va;
    *(f32x4*)(obB + c * 16 + g * 4) = vb2;
  }
}

extern "C" void kernel_launch(void* const* d_in, const int* in_sizes, int n_in,
                              void* d_out, int out_size, void* d_ws, size_t ws_size,
                              hipStream_t stream) {
  const float* x = (const float*)d_in[0];
  const float* text = (const float*)d_in[1];
  const float* Wq = (const float*)d_in[2];
  const float* bq = (const float*)d_in[3];
  const float* Wkv = (const float*)d_in[4];
  const float* bkv = (const float*)d_in[5];
  float* out = (float*)d_out;
  char* ws = (char*)d_ws;

  const size_t MiB = 1u << 20;
  u16* XB = (u16*)(ws + 0 * MiB);     // x bf16       [8192][1024]   16 MiB
  u16* TB = (u16*)(ws + 16 * MiB);    // text bf16    [8192][1024]   16 MiB
  u16* WQT = (u16*)(ws + 32 * MiB);   // Wq^T bf16    [1024][1024]    2 MiB
  u16* WKVT = (u16*)(ws + 34 * MiB);  // Wkv^T bf16   [2048][1024]    4 MiB
  u16* QG = (u16*)(ws + 38 * MiB);    // Q  bf16      [4][16][2048][64]
  u16* KG = (u16*)(ws + 54 * MiB);    // K  bf16      swizzled rows
  u16* VG = (u16*)(ws + 70 * MiB);    // V  f16       PV-fragment layout (end: 86 MiB)

  k_cast<<<2048, 256, 0, stream>>>(x, XB, 2097152);
  k_cast<<<2048, 256, 0, stream>>>(text, TB, 2097152);
  k_transpose_cast<<<dim3(32, 32), dim3(32, 8), 0, stream>>>(Wq, WQT, 1024, 1024);
  k_transpose_cast<<<dim3(64, 32), dim3(32, 8), 0, stream>>>(Wkv, WKVT, 1024, 2048);
  k_gemm<0><<<dim3(8, 64), 256, 0, stream>>>(XB, WQT, bq, QG, (u16*)nullptr);
  k_gemm<1><<<dim3(16, 64), 256, 0, stream>>>(TB, WKVT, bkv, KG, VG);
  k_attn<<<1024, 256, 0, stream>>>(QG, KG, VG, out);
}